// Round 10
// baseline (393.375 us; speedup 1.0000x reference)
//
#include <hip/hip_runtime.h>
#include <hip/hip_bf16.h>
#include <stdint.h>

#define B_ 4
#define S_ 2048
#define D_ 1024
#define M_ 4

typedef __bf16 bf16;
typedef _Float16 f16;
typedef unsigned char u8;
typedef __bf16 bf16x8 __attribute__((ext_vector_type(8)));
typedef _Float16 f16x8 __attribute__((ext_vector_type(8)));
typedef float f32x4 __attribute__((ext_vector_type(4)));

__device__ __forceinline__ void async_copy16(const void* g, void* l) {
  __builtin_amdgcn_global_load_lds(
      (const __attribute__((address_space(1))) void*)g,
      (__attribute__((address_space(3))) void*)l, 16, 0, 0);
}

// Fused prep, block ranges:
//   [0,4096)      : x fp32 -> bf16
//   [4096,5120)   : 4x W [1024,1024] fp32 -> WT bf16 (256 blocks each)
//   [5120,7168)   : pack 4 masks -> bitfield bytes
__global__ __launch_bounds__(256) void prep(
    const float* __restrict__ x, const float* __restrict__ w0,
    const float* __restrict__ w1, const float* __restrict__ w2,
    const float* __restrict__ w3, const int* __restrict__ masks,
    bf16* __restrict__ xc, bf16* __restrict__ WT, u8* __restrict__ pk) {
  __shared__ bf16 t[64][65];
  const int blk = blockIdx.x;
  const int tid = threadIdx.x;
  const long SS = (long)S_ * S_;

  if (blk < 4096) {  // x -> bf16
    const long i = (long)blk * 2048 + tid * 8;
    const float4 a = *(const float4*)(x + i);
    const float4 b = *(const float4*)(x + i + 4);
    bf16x8 o;
    o[0] = (bf16)a.x; o[1] = (bf16)a.y; o[2] = (bf16)a.z; o[3] = (bf16)a.w;
    o[4] = (bf16)b.x; o[5] = (bf16)b.y; o[6] = (bf16)b.z; o[7] = (bf16)b.w;
    *(bf16x8*)(xc + i) = o;
  } else if (blk < 5120) {  // weight transpose -> bf16
    const int local = blk - 4096;
    const int z = local >> 8;
    const int rem = local & 255;
    const int r0 = (rem >> 4) * 64;
    const int c0 = (rem & 15) * 64;
    const int tx = tid & 63;
    const int ty = tid >> 6;
    const float* in = (z == 0) ? w0 : (z == 1) ? w1 : (z == 2) ? w2 : w3;
    bf16* out = WT + (long)z * D_ * D_;
    for (int i = ty; i < 64; i += 4)
      t[i][tx] = (bf16)in[(long)(r0 + i) * D_ + c0 + tx];
    __syncthreads();
    for (int i = ty; i < 64; i += 4)
      out[(long)(c0 + i) * D_ + r0 + tx] = t[tx][i];
  } else {  // pack masks
    const long e = (long)(blk - 5120) * 2048 + tid * 8;
    unsigned long long wv = 0;
#pragma unroll
    for (int m = 0; m < M_; ++m) {
      const int4 a = *(const int4*)(masks + m * SS + e);
      const int4 b = *(const int4*)(masks + m * SS + e + 4);
      const int v[8] = {a.x, a.y, a.z, a.w, b.x, b.y, b.z, b.w};
#pragma unroll
      for (int j = 0; j < 8; ++j)
        wv |= (unsigned long long)(v[j] != 0 ? 1u : 0u) << (8 * j + m);
    }
    *(unsigned long long*)(pk + e) = wv;
  }
}

// batched bf16 [rows,cols] -> [cols,rows] transpose (z = batch)
__global__ __launch_bounds__(256) void transposeB(
    const bf16* __restrict__ in, bf16* __restrict__ out,
    int rows, int cols, long ib, long ob) {
  __shared__ bf16 t[64][65];
  in += (long)blockIdx.z * ib;
  out += (long)blockIdx.z * ob;
  const int r0 = blockIdx.y * 64;
  const int c0 = blockIdx.x * 64;
  const int tx = threadIdx.x & 63;
  const int ty = threadIdx.x >> 6;
#pragma unroll
  for (int i = ty; i < 64; i += 4) t[i][tx] = in[(long)(r0 + i) * cols + c0 + tx];
  __syncthreads();
#pragma unroll
  for (int i = ty; i < 64; i += 4) out[(long)(c0 + i) * rows + r0 + tx] = t[tx][i];
}

#define MODE_PLAIN 0
#define MODE_EXP 1   // C = exp(alpha*acc), f16 out; B z-batched by row0>>11
#define MODE_QKV 2   // N=3072 grouped epilogue: Q | K | V
#define MODE_PV 3    // B z-batched by row0>>11

// ---------- 256x128 3-slot rotating counted-vmcnt GEMM, 8 waves (PV/Wo) ----------
// r8-verified. 512 threads = 8 waves (4M x 2N), per-wave 64x64 (acc 4x4).
// LDS 72 KiB; ledger/swizzle documented in r8. Kept for the 256-block launches.
template <typename OutT, int MODE>
__global__ __launch_bounds__(512) void gemmA(
    const bf16* __restrict__ A, int lda,
    const bf16* __restrict__ Bt, long bzs, int ldb,
    OutT* __restrict__ C, int ldc,
    const float* __restrict__ bias0, const float* __restrict__ bias1,
    const float* __restrict__ bias2, float alpha, int K) {
  __shared__ __align__(16) bf16 As[3][256 * 32];
  __shared__ __align__(16) bf16 Bs[3][128 * 32];
  const int tid = threadIdx.x;
  const int lane = tid & 63;
  const int w = tid >> 6;
  const int wm = w & 3;
  const int wn = w >> 2;
  const int quad = lane >> 4;
  const int l15 = lane & 15;
  const int fse = (quad ^ ((l15 >> 1) & 3)) << 3;

  const int gx = gridDim.x;
  const int pid = blockIdx.y * gx + blockIdx.x;
  const int gsz = 8 * gx;
  const int bym = (pid / gsz) * 8 + (pid % 8);
  const int bxm = (pid % gsz) / 8;
  const int row0 = bym * 256;
  const int col0 = bxm * 128;

  const bf16* Arow = A + (long)row0 * lda;
  const bf16* Bcol;
  int grp = 0;
  if (MODE == MODE_QKV) {
    grp = col0 >> 10;
    Bcol = Bt + (long)grp * ((long)D_ * D_) + (long)(col0 & (D_ - 1)) * ldb;
  } else if (MODE == MODE_PV || MODE == MODE_EXP) {
    Bcol = Bt + (long)(row0 >> 11) * bzs + (long)col0 * ldb;
  } else {
    Bcol = Bt + (long)col0 * ldb;
  }

  const int sr = tid >> 2;
  const int sc = ((tid & 3) ^ ((tid >> 3) & 3)) << 3;
  const bf16* gA = Arow + (long)sr * lda + sc;
  const bf16* gB = Bcol + (long)sr * ldb + sc;
  const int dstoff = (tid >> 6) << 9;
  const long a128 = (long)128 * lda;

#define STAGE(h, s)                                                    \
  {                                                                    \
    const int kc_ = (h) * 32;                                          \
    bf16* da_ = &As[0][0] + (s) * (256 * 32) + dstoff;                 \
    bf16* db_ = &Bs[0][0] + (s) * (128 * 32) + dstoff;                 \
    async_copy16(gA + kc_, da_);                                       \
    async_copy16(gA + kc_ + a128, da_ + 4096);                         \
    async_copy16(gB + kc_, db_);                                       \
  }

#define READF(Ra, Rb, s)                                                   \
  {                                                                        \
    const bf16* pa_ = &As[0][0] + (s) * (256 * 32);                        \
    const bf16* pb_ = &Bs[0][0] + (s) * (128 * 32);                        \
    _Pragma("unroll") for (int j = 0; j < 4; ++j) {                        \
      Ra[j] = *(const bf16x8*)&pa_[(wm * 64 + j * 16 + l15) * 32 + fse];   \
      Rb[j] = *(const bf16x8*)&pb_[(wn * 64 + j * 16 + l15) * 32 + fse];   \
    }                                                                      \
  }

#define MM(Ra, Rb)                                                         \
  __builtin_amdgcn_s_setprio(1);                                           \
  _Pragma("unroll") for (int mi = 0; mi < 4; ++mi)                         \
      _Pragma("unroll") for (int ni = 0; ni < 4; ++ni) acc[mi][ni] =       \
          __builtin_amdgcn_mfma_f32_16x16x32_bf16(Ra[mi], Rb[ni],          \
                                                  acc[mi][ni], 0, 0, 0);   \
  __builtin_amdgcn_s_setprio(0);

  f32x4 acc[4][4];
#pragma unroll
  for (int i = 0; i < 4; ++i)
#pragma unroll
    for (int j = 0; j < 4; ++j) acc[i][j] = (f32x4){0.f, 0.f, 0.f, 0.f};

  const int nh = (K >> 6) << 1;

  STAGE(0, 0);
  STAGE(1, 1);
  asm volatile("s_waitcnt vmcnt(3)" ::: "memory");
  __builtin_amdgcn_s_barrier();
  __builtin_amdgcn_sched_barrier(0);

  int s0 = 0;
  for (int h = 0; h < nh; ++h) {
    bf16x8 af[4], bf[4];
    READF(af, bf, s0);
    if (h + 2 < nh) {
      const int s2 = (s0 >= 1) ? (s0 - 1) : 2;
      STAGE(h + 2, s2);
    }
    MM(af, bf);
    if (h + 2 < nh)
      asm volatile("s_waitcnt vmcnt(3)" ::: "memory");
    else if (h + 1 < nh)
      asm volatile("s_waitcnt vmcnt(0)" ::: "memory");
    if (h + 1 < nh) {
      __builtin_amdgcn_s_barrier();
      __builtin_amdgcn_sched_barrier(0);
    }
    s0 = (s0 == 2) ? 0 : (s0 + 1);
  }

#undef STAGE
#undef READF
#undef MM

  const float* bias = (MODE == MODE_QKV)
                          ? (grp == 0 ? bias0 : grp == 1 ? bias1 : bias2)
                          : bias0;
  const long NX = (long)B_ * S_ * D_;
  OutT* Cb = (MODE == MODE_QKV) ? C + (long)grp * NX : C;
#pragma unroll
  for (int mi = 0; mi < 4; ++mi)
#pragma unroll
    for (int ni = 0; ni < 4; ++ni) {
      const int col = col0 + wn * 64 + ni * 16 + l15;
      const int ccol = (MODE == MODE_QKV) ? (col & (D_ - 1)) : col;
      const float bv = bias ? bias[ccol] : 0.0f;
#pragma unroll
      for (int r = 0; r < 4; ++r) {
        const int row = row0 + wm * 64 + mi * 16 + quad * 4 + r;
        const float val = acc[mi][ni][r] * alpha + bv;
        if (MODE == MODE_EXP) {
          Cb[(long)row * ldc + col] = (OutT)__expf(val);
        } else if (MODE == MODE_QKV) {
          Cb[(long)row * D_ + ccol] = (OutT)val;
        } else {
          Cb[(long)row * ldc + col] = (OutT)val;
        }
      }
    }
}

// ------- 256x128 3-slot GEMM, 4 waves of 128x64 (QKV/EXP; fat wave tiles) -------
// r8 measured QKV at the LDS-read roofline of the 64x64-wave geometry:
// 791 cyc/phase-slot vs floor 768 (8 waves x 8 ds_read_b128 x 12 cyc), MFMA 621.
// Fatter wave tile cuts LDS bytes/FLOP 1.5x: 4 waves, each owns 128x64
// (acc 8x4, 32 MFMA/phase, 12 ds_read/phase).
// Per block-phase: LDS 4x12x12=576 cyc < MFMA 4x32x4.85=621 -> MFMA-bound.
// Same 72 KiB 3-slot LDS -> still 2 blocks/CU; cross-block overlap
// (r8-verified mechanism) hides one block's reads under the other's MFMA.
// STAGE: 256 threads, 6 loads/thread (A 4 rounds of 64 rows, B 2 rounds).
// vmcnt ledger (6 loads/stage): steady outstanding {h+1,h+2}=12 -> vmcnt(6)
// retires h+1; tail publish -> vmcnt(0). Prologue stages 0,1 -> vmcnt(6).
// WAR/RAW/swizzle identical to gemmA (staging row = tid>>2 + 64k, 64k doesn't
// touch bits 1-2 -> same XOR bits; frag row = X*16+l15 -> (row>>1)&3=(l15>>1)&3).
// r9 audit (post container-failure): DMA row mapping (tid>>6)*16+((tid&63)>>2)+64r
// == staged global row (tid>>2)+64r identically; LDS extents exactly fill As/Bs;
// ledger and barrier uniformity re-verified. Resubmitted byte-identical as the
// kernel-vs-infra discriminator; if it fails again, gemmB is abandoned.
template <typename OutT, int MODE>
__global__ __launch_bounds__(256) void gemmB(
    const bf16* __restrict__ A, int lda,
    const bf16* __restrict__ Bt, long bzs, int ldb,
    OutT* __restrict__ C, int ldc,
    const float* __restrict__ bias0, const float* __restrict__ bias1,
    const float* __restrict__ bias2, float alpha, int K) {
  __shared__ __align__(16) bf16 As[3][256 * 32];
  __shared__ __align__(16) bf16 Bs[3][128 * 32];
  const int tid = threadIdx.x;
  const int lane = tid & 63;
  const int w = tid >> 6;   // 0..3
  const int wm = w & 1;     // row half: rows wm*128..+128
  const int wn = w >> 1;    // col half: cols wn*64..+64
  const int quad = lane >> 4;
  const int l15 = lane & 15;
  const int fse = (quad ^ ((l15 >> 1) & 3)) << 3;

  // GROUP-8 M-swizzle (gridDim.y = 32 in all launches)
  const int gx = gridDim.x;
  const int pid = blockIdx.y * gx + blockIdx.x;
  const int gsz = 8 * gx;
  const int bym = (pid / gsz) * 8 + (pid % 8);
  const int bxm = (pid % gsz) / 8;
  const int row0 = bym * 256;
  const int col0 = bxm * 128;

  const bf16* Arow = A + (long)row0 * lda;
  const bf16* Bcol;
  int grp = 0;
  if (MODE == MODE_QKV) {
    grp = col0 >> 10;
    Bcol = Bt + (long)grp * ((long)D_ * D_) + (long)(col0 & (D_ - 1)) * ldb;
  } else if (MODE == MODE_PV || MODE == MODE_EXP) {
    Bcol = Bt + (long)(row0 >> 11) * bzs + (long)col0 * ldb;
  } else {
    Bcol = Bt + (long)col0 * ldb;
  }

  // staging: 256 threads, rows sr + 64k; pre-swizzled source col
  const int sr = tid >> 2;                             // 0..63
  const int sc = ((tid & 3) ^ ((tid >> 3) & 3)) << 3;  // swizzled 16B slot
  const bf16* gA = Arow + (long)sr * lda + sc;
  const bf16* gB = Bcol + (long)sr * ldb + sc;
  const int dstoff = (tid >> 6) << 9;  // wave base (elems; 4 waves x 1KB/round)
  const long a64 = (long)64 * lda;
  const long b64 = (long)64 * ldb;

#define STAGE(h, s)                                                    \
  {                                                                    \
    const int kc_ = (h) * 32;                                          \
    bf16* da_ = &As[0][0] + (s) * (256 * 32) + dstoff;                 \
    bf16* db_ = &Bs[0][0] + (s) * (128 * 32) + dstoff;                 \
    async_copy16(gA + kc_, da_);                                       \
    async_copy16(gA + kc_ + a64, da_ + 2048);                          \
    async_copy16(gA + kc_ + 2 * a64, da_ + 4096);                      \
    async_copy16(gA + kc_ + 3 * a64, da_ + 6144);                      \
    async_copy16(gB + kc_, db_);                                       \
    async_copy16(gB + kc_ + b64, db_ + 2048);                          \
  }

#define READF(Ra, Rb, s)                                                    \
  {                                                                         \
    const bf16* pa_ = &As[0][0] + (s) * (256 * 32);                         \
    const bf16* pb_ = &Bs[0][0] + (s) * (128 * 32);                         \
    _Pragma("unroll") for (int j = 0; j < 8; ++j)                           \
        Ra[j] = *(const bf16x8*)&pa_[(wm * 128 + j * 16 + l15) * 32 + fse]; \
    _Pragma("unroll") for (int j = 0; j < 4; ++j)                           \
        Rb[j] = *(const bf16x8*)&pb_[(wn * 64 + j * 16 + l15) * 32 + fse];  \
  }

#define MM(Ra, Rb)                                                         \
  __builtin_amdgcn_s_setprio(1);                                           \
  _Pragma("unroll") for (int mi = 0; mi < 8; ++mi)                         \
      _Pragma("unroll") for (int ni = 0; ni < 4; ++ni) acc[mi][ni] =       \
          __builtin_amdgcn_mfma_f32_16x16x32_bf16(Ra[mi], Rb[ni],          \
                                                  acc[mi][ni], 0, 0, 0);   \
  __builtin_amdgcn_s_setprio(0);

  f32x4 acc[8][4];
#pragma unroll
  for (int i = 0; i < 8; ++i)
#pragma unroll
    for (int j = 0; j < 4; ++j) acc[i][j] = (f32x4){0.f, 0.f, 0.f, 0.f};

  const int nh = (K >> 6) << 1;

  // prologue: stage halves 0,1 (12 loads); publish half 0 (retire 6).
  STAGE(0, 0);
  STAGE(1, 1);
  asm volatile("s_waitcnt vmcnt(6)" ::: "memory");
  __builtin_amdgcn_s_barrier();
  __builtin_amdgcn_sched_barrier(0);

  int s0 = 0;
  for (int h = 0; h < nh; ++h) {
    bf16x8 af[8], bf[4];
    READF(af, bf, s0);
    if (h + 2 < nh) {
      const int s2 = (s0 >= 1) ? (s0 - 1) : 2;
      STAGE(h + 2, s2);
    }
    MM(af, bf);
    if (h + 2 < nh)
      asm volatile("s_waitcnt vmcnt(6)" ::: "memory");
    else if (h + 1 < nh)
      asm volatile("s_waitcnt vmcnt(0)" ::: "memory");
    if (h + 1 < nh) {
      __builtin_amdgcn_s_barrier();
      __builtin_amdgcn_sched_barrier(0);
    }
    s0 = (s0 == 2) ? 0 : (s0 + 1);
  }

#undef STAGE
#undef READF
#undef MM

  // epilogue: C/D layout col = lane&15, row = quad*4 + reg
  const float* bias = (MODE == MODE_QKV)
                          ? (grp == 0 ? bias0 : grp == 1 ? bias1 : bias2)
                          : bias0;
  const long NX = (long)B_ * S_ * D_;
  OutT* Cb = (MODE == MODE_QKV) ? C + (long)grp * NX : C;
#pragma unroll
  for (int mi = 0; mi < 8; ++mi)
#pragma unroll
    for (int ni = 0; ni < 4; ++ni) {
      const int col = col0 + wn * 64 + ni * 16 + l15;
      const int ccol = (MODE == MODE_QKV) ? (col & (D_ - 1)) : col;
      const float bv = bias ? bias[ccol] : 0.0f;
#pragma unroll
      for (int r = 0; r < 4; ++r) {
        const int row = row0 + wm * 128 + mi * 16 + quad * 4 + r;
        const float val = acc[mi][ni][r] * alpha + bv;
        if (MODE == MODE_EXP) {
          Cb[(long)row * ldc + col] = (OutT)__expf(val);
        } else if (MODE == MODE_QKV) {
          Cb[(long)row * D_ + ccol] = (OutT)val;
        } else {
          Cb[(long)row * ldc + col] = (OutT)val;
        }
      }
    }
}

// grid (S, B): P[b,q,:] = E[b,q,:] * sum_m bit_m(q,:) / rowsum_m / M, bf16.
__global__ __launch_bounds__(256) void softmax_combine(
    const f16* __restrict__ E, const u8* __restrict__ pk, bf16* __restrict__ P) {
  const int q = blockIdx.x;
  const int b = blockIdx.y;
  const int tid = threadIdx.x;
  const int lane = tid & 63;
  const int wv = tid >> 6;
  __shared__ float4 red[4];

  float e[8];
  {
    const f16x8 h = *(const f16x8*)(E + ((long)b * S_ + q) * S_ + tid * 8);
#pragma unroll
    for (int j = 0; j < 8; ++j) e[j] = (float)h[j];
  }
  const unsigned long long mb =
      *(const unsigned long long*)(pk + (long)q * S_ + tid * 8);

  float4 s = {0.f, 0.f, 0.f, 0.f};
#pragma unroll
  for (int j = 0; j < 8; ++j) {
    const unsigned bits = (unsigned)(mb >> (8 * j)) & 0xF;
    const float ev = e[j];
    if (bits & 1) s.x += ev;
    if (bits & 2) s.y += ev;
    if (bits & 4) s.z += ev;
    if (bits & 8) s.w += ev;
  }
#pragma unroll
  for (int o = 32; o > 0; o >>= 1) {
    s.x += __shfl_xor(s.x, o, 64);
    s.y += __shfl_xor(s.y, o, 64);
    s.z += __shfl_xor(s.z, o, 64);
    s.w += __shfl_xor(s.w, o, 64);
  }
  if (lane == 0) red[wv] = s;
  __syncthreads();
  const float4 t0 = red[0], t1 = red[1], t2 = red[2], t3 = red[3];
  const float r0 = 0.25f / (t0.x + t1.x + t2.x + t3.x);
  const float r1 = 0.25f / (t0.y + t1.y + t2.y + t3.y);
  const float r2 = 0.25f / (t0.z + t1.z + t2.z + t3.z);
  const float r3 = 0.25f / (t0.w + t1.w + t2.w + t3.w);

  bf16x8 o;
#pragma unroll
  for (int j = 0; j < 8; ++j) {
    const unsigned bits = (unsigned)(mb >> (8 * j)) & 0xF;
    const float wgt = ((bits & 1) ? r0 : 0.f) + ((bits & 2) ? r1 : 0.f) +
                      ((bits & 4) ? r2 : 0.f) + ((bits & 8) ? r3 : 0.f);
    o[j] = (bf16)(e[j] * wgt);
  }
  *(bf16x8*)(P + ((long)b * S_ + q) * S_ + tid * 8) = o;
}

extern "C" void kernel_launch(void* const* d_in, const int* in_sizes, int n_in,
                              void* d_out, int out_size, void* d_ws, size_t ws_size,
                              hipStream_t stream) {
  const float* x = (const float*)d_in[0];
  const int* masks = (const int*)d_in[1];
  const float* bq = (const float*)d_in[3];
  const float* bk = (const float*)d_in[5];
  const float* bv = (const float*)d_in[7];
  const float* bo = (const float*)d_in[9];
  float* out = (float*)d_out;

  const long DD = (long)D_ * D_;
  const long SD = (long)S_ * D_;
  const long NX = (long)B_ * SD;
  const long SS = (long)S_ * S_;

  // ws: xc 16M | WT 8M | pk 4M | Q/K/V 48M | VT 16M | P 32M | E 32M = 156 MiB
  bf16* xc = (bf16*)d_ws;
  bf16* WqT = xc + NX;  // WkT, WvT, WoT contiguous after
  bf16* WoT = WqT + 3 * DD;
  u8* pk = (u8*)(WoT + DD);    // [S][S] mask bitfield
  bf16* Q = (bf16*)(pk + SS);  // K = Q+NX, V = K+NX (QKV epilogue relies on it)
  bf16* K = Q + NX;
  bf16* V = K + NX;
  bf16* VT = V + NX;
  bf16* P = VT + NX;                   // [B][S][S] bf16
  f16* E = (f16*)(P + (long)B_ * SS);  // [B][S][S] f16
  bf16* attn = Q;                      // attn overwrites dead Q

  dim3 blk(256);
  dim3 blk512(512);

  // fused prep: x->bf16, 4 weight transposes, mask pack (one launch)
  prep<<<dim3(7168), blk, 0, stream>>>(
      x, (const float*)d_in[2], (const float*)d_in[4], (const float*)d_in[6],
      (const float*)d_in[8], masks, xc, WqT, pk);

  // fused Q|K|V projection: [8192,1024] x [1024,3072], 256x128 tiles
  // 4-wave fat-tile variant; 768 blocks, 2 blocks/CU
  gemmB<bf16, MODE_QKV><<<dim3(24, 32), blk, 0, stream>>>(
      xc, D_, WqT, 0, D_, Q, D_, bq, bk, bv, 1.0f, D_);

  // VT[b][d][s] = V[b][s][d]
  transposeB<<<dim3(16, 32, B_), blk, 0, stream>>>(V, VT, S_, D_, SD, SD);

  // E = exp(Q K^T / 32) : flat [8192,1024] x K[z][2048,1024], z = row>>11
  // 4-wave fat-tile variant; 512 blocks = 1 exact round at 2 blocks/CU
  gemmB<f16, MODE_EXP><<<dim3(16, 32), blk, 0, stream>>>(
      Q, D_, K, SD, D_, E, S_, nullptr, nullptr, nullptr, 1.0f / 32.0f, D_);

  // P = E * sum_m mask_m / rowsum_m / M
  softmax_combine<<<dim3(S_, B_), blk, 0, stream>>>(E, pk, P);

  // attn = P @ V : flat [8192,2048] x VT[z][1024,2048], K=2048 (r8 gemmA)
  gemmA<bf16, MODE_PV><<<dim3(8, 32), blk512, 0, stream>>>(
      P, S_, VT, SD, S_, attn, D_, nullptr, nullptr, nullptr, 1.0f, S_);

  // out = attn @ Wo + bo : fp32 epilogue straight to d_out (r8 gemmA)
  gemmA<float, MODE_PLAIN><<<dim3(8, 32), blk512, 0, stream>>>(
      attn, D_, WoT, 0, D_, out, D_, bo, nullptr, nullptr, 1.0f, D_);
}

// Round 11
// 357.680 us; speedup vs baseline: 1.0998x; 1.0998x over previous
//
#include <hip/hip_runtime.h>
#include <hip/hip_bf16.h>
#include <stdint.h>

#define B_ 4
#define S_ 2048
#define D_ 1024
#define M_ 4

typedef __bf16 bf16;
typedef _Float16 f16;
typedef unsigned char u8;
typedef __bf16 bf16x8 __attribute__((ext_vector_type(8)));
typedef _Float16 f16x8 __attribute__((ext_vector_type(8)));
typedef float f32x4 __attribute__((ext_vector_type(4)));

__device__ __forceinline__ void async_copy16(const void* g, void* l) {
  __builtin_amdgcn_global_load_lds(
      (const __attribute__((address_space(1))) void*)g,
      (__attribute__((address_space(3))) void*)l, 16, 0, 0);
}

// Fused prep, block ranges:
//   [0,4096)      : x fp32 -> bf16
//   [4096,5120)   : 4x W [1024,1024] fp32 -> WT bf16 (256 blocks each)
//   [5120,7168)   : pack 4 masks -> bitfield bytes
__global__ __launch_bounds__(256) void prep(
    const float* __restrict__ x, const float* __restrict__ w0,
    const float* __restrict__ w1, const float* __restrict__ w2,
    const float* __restrict__ w3, const int* __restrict__ masks,
    bf16* __restrict__ xc, bf16* __restrict__ WT, u8* __restrict__ pk) {
  __shared__ bf16 t[64][65];
  const int blk = blockIdx.x;
  const int tid = threadIdx.x;
  const long SS = (long)S_ * S_;

  if (blk < 4096) {  // x -> bf16
    const long i = (long)blk * 2048 + tid * 8;
    const float4 a = *(const float4*)(x + i);
    const float4 b = *(const float4*)(x + i + 4);
    bf16x8 o;
    o[0] = (bf16)a.x; o[1] = (bf16)a.y; o[2] = (bf16)a.z; o[3] = (bf16)a.w;
    o[4] = (bf16)b.x; o[5] = (bf16)b.y; o[6] = (bf16)b.z; o[7] = (bf16)b.w;
    *(bf16x8*)(xc + i) = o;
  } else if (blk < 5120) {  // weight transpose -> bf16
    const int local = blk - 4096;
    const int z = local >> 8;
    const int rem = local & 255;
    const int r0 = (rem >> 4) * 64;
    const int c0 = (rem & 15) * 64;
    const int tx = tid & 63;
    const int ty = tid >> 6;
    const float* in = (z == 0) ? w0 : (z == 1) ? w1 : (z == 2) ? w2 : w3;
    bf16* out = WT + (long)z * D_ * D_;
    for (int i = ty; i < 64; i += 4)
      t[i][tx] = (bf16)in[(long)(r0 + i) * D_ + c0 + tx];
    __syncthreads();
    for (int i = ty; i < 64; i += 4)
      out[(long)(c0 + i) * D_ + r0 + tx] = t[tx][i];
  } else {  // pack masks
    const long e = (long)(blk - 5120) * 2048 + tid * 8;
    unsigned long long wv = 0;
#pragma unroll
    for (int m = 0; m < M_; ++m) {
      const int4 a = *(const int4*)(masks + m * SS + e);
      const int4 b = *(const int4*)(masks + m * SS + e + 4);
      const int v[8] = {a.x, a.y, a.z, a.w, b.x, b.y, b.z, b.w};
#pragma unroll
      for (int j = 0; j < 8; ++j)
        wv |= (unsigned long long)(v[j] != 0 ? 1u : 0u) << (8 * j + m);
    }
    *(unsigned long long*)(pk + e) = wv;
  }
}

// batched bf16 [rows,cols] -> [cols,rows] transpose (z = batch)
__global__ __launch_bounds__(256) void transposeB(
    const bf16* __restrict__ in, bf16* __restrict__ out,
    int rows, int cols, long ib, long ob) {
  __shared__ bf16 t[64][65];
  in += (long)blockIdx.z * ib;
  out += (long)blockIdx.z * ob;
  const int r0 = blockIdx.y * 64;
  const int c0 = blockIdx.x * 64;
  const int tx = threadIdx.x & 63;
  const int ty = threadIdx.x >> 6;
#pragma unroll
  for (int i = ty; i < 64; i += 4) t[i][tx] = in[(long)(r0 + i) * cols + c0 + tx];
  __syncthreads();
#pragma unroll
  for (int i = ty; i < 64; i += 4) out[(long)(c0 + i) * rows + r0 + tx] = t[tx][i];
}

#define MODE_PLAIN 0
#define MODE_EXP 1   // C = exp(alpha*acc), f16 out; B z-batched by row0>>11
#define MODE_QKV 2   // N=3072 grouped epilogue: Q | K | V
#define MODE_PV 3    // B z-batched by row0>>11

// ---------- 256x128 3-slot rotating counted-vmcnt GEMM, 8 waves (QKV/EXP) ----------
// r8-verified at 2 blocks/CU: 791 cyc/phase-slot = LDS-read floor (768).
// Lesson from r10: wave/SIMD density >= 4 beats LDS-bytes/FLOP — the 4-wave
// fat-tile variant (2 waves/SIMD) collapsed to 4730 cyc/slot. Keep this geometry.
// 512 threads = 8 waves (4M x 2N), per-wave 64x64 (acc 4x4). LDS 72 KiB.
template <typename OutT, int MODE>
__global__ __launch_bounds__(512) void gemmA(
    const bf16* __restrict__ A, int lda,
    const bf16* __restrict__ Bt, long bzs, int ldb,
    OutT* __restrict__ C, int ldc,
    const float* __restrict__ bias0, const float* __restrict__ bias1,
    const float* __restrict__ bias2, float alpha, int K) {
  __shared__ __align__(16) bf16 As[3][256 * 32];
  __shared__ __align__(16) bf16 Bs[3][128 * 32];
  const int tid = threadIdx.x;
  const int lane = tid & 63;
  const int w = tid >> 6;
  const int wm = w & 3;
  const int wn = w >> 2;
  const int quad = lane >> 4;
  const int l15 = lane & 15;
  const int fse = (quad ^ ((l15 >> 1) & 3)) << 3;

  const int gx = gridDim.x;
  const int pid = blockIdx.y * gx + blockIdx.x;
  const int gsz = 8 * gx;
  const int bym = (pid / gsz) * 8 + (pid % 8);
  const int bxm = (pid % gsz) / 8;
  const int row0 = bym * 256;
  const int col0 = bxm * 128;

  const bf16* Arow = A + (long)row0 * lda;
  const bf16* Bcol;
  int grp = 0;
  if (MODE == MODE_QKV) {
    grp = col0 >> 10;
    Bcol = Bt + (long)grp * ((long)D_ * D_) + (long)(col0 & (D_ - 1)) * ldb;
  } else if (MODE == MODE_PV || MODE == MODE_EXP) {
    Bcol = Bt + (long)(row0 >> 11) * bzs + (long)col0 * ldb;
  } else {
    Bcol = Bt + (long)col0 * ldb;
  }

  const int sr = tid >> 2;
  const int sc = ((tid & 3) ^ ((tid >> 3) & 3)) << 3;
  const bf16* gA = Arow + (long)sr * lda + sc;
  const bf16* gB = Bcol + (long)sr * ldb + sc;
  const int dstoff = (tid >> 6) << 9;
  const long a128 = (long)128 * lda;

#define STAGE(h, s)                                                    \
  {                                                                    \
    const int kc_ = (h) * 32;                                          \
    bf16* da_ = &As[0][0] + (s) * (256 * 32) + dstoff;                 \
    bf16* db_ = &Bs[0][0] + (s) * (128 * 32) + dstoff;                 \
    async_copy16(gA + kc_, da_);                                       \
    async_copy16(gA + kc_ + a128, da_ + 4096);                         \
    async_copy16(gB + kc_, db_);                                       \
  }

#define READF(Ra, Rb, s)                                                   \
  {                                                                        \
    const bf16* pa_ = &As[0][0] + (s) * (256 * 32);                        \
    const bf16* pb_ = &Bs[0][0] + (s) * (128 * 32);                        \
    _Pragma("unroll") for (int j = 0; j < 4; ++j) {                        \
      Ra[j] = *(const bf16x8*)&pa_[(wm * 64 + j * 16 + l15) * 32 + fse];   \
      Rb[j] = *(const bf16x8*)&pb_[(wn * 64 + j * 16 + l15) * 32 + fse];   \
    }                                                                      \
  }

#define MM(Ra, Rb)                                                         \
  __builtin_amdgcn_s_setprio(1);                                           \
  _Pragma("unroll") for (int mi = 0; mi < 4; ++mi)                         \
      _Pragma("unroll") for (int ni = 0; ni < 4; ++ni) acc[mi][ni] =       \
          __builtin_amdgcn_mfma_f32_16x16x32_bf16(Ra[mi], Rb[ni],          \
                                                  acc[mi][ni], 0, 0, 0);   \
  __builtin_amdgcn_s_setprio(0);

  f32x4 acc[4][4];
#pragma unroll
  for (int i = 0; i < 4; ++i)
#pragma unroll
    for (int j = 0; j < 4; ++j) acc[i][j] = (f32x4){0.f, 0.f, 0.f, 0.f};

  const int nh = (K >> 6) << 1;

  STAGE(0, 0);
  STAGE(1, 1);
  asm volatile("s_waitcnt vmcnt(3)" ::: "memory");
  __builtin_amdgcn_s_barrier();
  __builtin_amdgcn_sched_barrier(0);

  int s0 = 0;
  for (int h = 0; h < nh; ++h) {
    bf16x8 af[4], bf[4];
    READF(af, bf, s0);
    if (h + 2 < nh) {
      const int s2 = (s0 >= 1) ? (s0 - 1) : 2;
      STAGE(h + 2, s2);
    }
    MM(af, bf);
    if (h + 2 < nh)
      asm volatile("s_waitcnt vmcnt(3)" ::: "memory");
    else if (h + 1 < nh)
      asm volatile("s_waitcnt vmcnt(0)" ::: "memory");
    if (h + 1 < nh) {
      __builtin_amdgcn_s_barrier();
      __builtin_amdgcn_sched_barrier(0);
    }
    s0 = (s0 == 2) ? 0 : (s0 + 1);
  }

#undef STAGE
#undef READF
#undef MM

  const float* bias = (MODE == MODE_QKV)
                          ? (grp == 0 ? bias0 : grp == 1 ? bias1 : bias2)
                          : bias0;
  const long NX = (long)B_ * S_ * D_;
  OutT* Cb = (MODE == MODE_QKV) ? C + (long)grp * NX : C;
#pragma unroll
  for (int mi = 0; mi < 4; ++mi)
#pragma unroll
    for (int ni = 0; ni < 4; ++ni) {
      const int col = col0 + wn * 64 + ni * 16 + l15;
      const int ccol = (MODE == MODE_QKV) ? (col & (D_ - 1)) : col;
      const float bv = bias ? bias[ccol] : 0.0f;
#pragma unroll
      for (int r = 0; r < 4; ++r) {
        const int row = row0 + wm * 64 + mi * 16 + quad * 4 + r;
        const float val = acc[mi][ni][r] * alpha + bv;
        if (MODE == MODE_EXP) {
          Cb[(long)row * ldc + col] = (OutT)__expf(val);
        } else if (MODE == MODE_QKV) {
          Cb[(long)row * D_ + ccol] = (OutT)val;
        } else {
          Cb[(long)row * ldc + col] = (OutT)val;
        }
      }
    }
}

// ---------- 256x64 3-slot GEMM, 8 waves (PV/Wo): 2 blocks/CU for 256-block shapes ----------
// PV/Wo have N=1024 -> only 256 blocks at BN=128 = 1 block/CU = no cross-block
// overlap partner (r8's proven mechanism). Halving BN to 64 gives 512 blocks and
// LDS As 48K + Bs[3][64*32] 12K = 60 KiB -> 2 blocks/CU, keeping gemmA's
// 8-wave geometry (4 waves/SIMD on the CU — the r10 law).
// Per-wave 64x32: acc 4x2, 8 MFMA/phase, 6 ds_read/phase.
// Staging: A = 512 thr x 2 loads (as gemmA). B = 64 rows x 32 cols = 4 KB ->
// waves 0-3 only (wave-uniform branch); DMA row map w*16 + (lane>>2) ==
// staged global row tid>>2 for tid<256; swizzle bits from row bits 1-2 = l15
// bits 1-2 (frag rows wn*32+j*16+l15) — consistent with fse.
// vmcnt ledger is PER-WAVE: waves 0-3 issue 3 loads/stage -> steady vmcnt(3);
// waves 4-7 issue 2 -> steady vmcnt(2); tails vmcnt(0). Branches are
// wave-uniform; barriers sit outside all branches.
template <typename OutT, int MODE>
__global__ __launch_bounds__(512) void gemmC(
    const bf16* __restrict__ A, int lda,
    const bf16* __restrict__ Bt, long bzs, int ldb,
    OutT* __restrict__ C, int ldc,
    const float* __restrict__ bias0, float alpha, int K) {
  __shared__ __align__(16) bf16 As[3][256 * 32];
  __shared__ __align__(16) bf16 Bs[3][64 * 32];
  const int tid = threadIdx.x;
  const int lane = tid & 63;
  const int w = tid >> 6;
  const int wm = w & 3;   // rows wm*64..+64
  const int wn = w >> 2;  // cols wn*32..+32
  const int quad = lane >> 4;
  const int l15 = lane & 15;
  const int fse = (quad ^ ((l15 >> 1) & 3)) << 3;

  // GROUP-8 M-swizzle (gridDim.y = 32)
  const int gx = gridDim.x;
  const int pid = blockIdx.y * gx + blockIdx.x;
  const int gsz = 8 * gx;
  const int bym = (pid / gsz) * 8 + (pid % 8);
  const int bxm = (pid % gsz) / 8;
  const int row0 = bym * 256;
  const int col0 = bxm * 64;

  const bf16* Arow = A + (long)row0 * lda;
  const bf16* Bcol = (MODE == MODE_PV)
                         ? Bt + (long)(row0 >> 11) * bzs + (long)col0 * ldb
                         : Bt + (long)col0 * ldb;

  const int sr = tid >> 2;
  const int sc = ((tid & 3) ^ ((tid >> 3) & 3)) << 3;
  const bf16* gA = Arow + (long)sr * lda + sc;
  const bf16* gB = Bcol + (long)sr * ldb + sc;  // only waves 0-3 dereference
  const int dstoff = (tid >> 6) << 9;
  const long a128 = (long)128 * lda;
  const bool bstage = (w < 4);

#define STAGE(h, s)                                                    \
  {                                                                    \
    const int kc_ = (h) * 32;                                          \
    bf16* da_ = &As[0][0] + (s) * (256 * 32) + dstoff;                 \
    async_copy16(gA + kc_, da_);                                       \
    async_copy16(gA + kc_ + a128, da_ + 4096);                         \
    if (bstage) {                                                      \
      bf16* db_ = &Bs[0][0] + (s) * (64 * 32) + dstoff;                \
      async_copy16(gB + kc_, db_);                                     \
    }                                                                  \
  }

#define VMW(n3, n2)                                                    \
  if (bstage)                                                          \
    asm volatile("s_waitcnt vmcnt(" #n3 ")" ::: "memory");             \
  else                                                                 \
    asm volatile("s_waitcnt vmcnt(" #n2 ")" ::: "memory");

#define READF(Ra, Rb, s)                                                   \
  {                                                                        \
    const bf16* pa_ = &As[0][0] + (s) * (256 * 32);                        \
    const bf16* pb_ = &Bs[0][0] + (s) * (64 * 32);                         \
    _Pragma("unroll") for (int j = 0; j < 4; ++j)                          \
        Ra[j] = *(const bf16x8*)&pa_[(wm * 64 + j * 16 + l15) * 32 + fse]; \
    _Pragma("unroll") for (int j = 0; j < 2; ++j)                          \
        Rb[j] = *(const bf16x8*)&pb_[(wn * 32 + j * 16 + l15) * 32 + fse]; \
  }

#define MM(Ra, Rb)                                                         \
  __builtin_amdgcn_s_setprio(1);                                           \
  _Pragma("unroll") for (int mi = 0; mi < 4; ++mi)                         \
      _Pragma("unroll") for (int ni = 0; ni < 2; ++ni) acc[mi][ni] =       \
          __builtin_amdgcn_mfma_f32_16x16x32_bf16(Ra[mi], Rb[ni],          \
                                                  acc[mi][ni], 0, 0, 0);   \
  __builtin_amdgcn_s_setprio(0);

  f32x4 acc[4][2];
#pragma unroll
  for (int i = 0; i < 4; ++i)
#pragma unroll
    for (int j = 0; j < 2; ++j) acc[i][j] = (f32x4){0.f, 0.f, 0.f, 0.f};

  const int nh = (K >> 6) << 1;

  STAGE(0, 0);
  STAGE(1, 1);
  VMW(3, 2);
  __builtin_amdgcn_s_barrier();
  __builtin_amdgcn_sched_barrier(0);

  int s0 = 0;
  for (int h = 0; h < nh; ++h) {
    bf16x8 af[4], bf[2];
    READF(af, bf, s0);
    if (h + 2 < nh) {
      const int s2 = (s0 >= 1) ? (s0 - 1) : 2;
      STAGE(h + 2, s2);
    }
    MM(af, bf);
    if (h + 2 < nh) {
      VMW(3, 2);
    } else if (h + 1 < nh) {
      asm volatile("s_waitcnt vmcnt(0)" ::: "memory");
    }
    if (h + 1 < nh) {
      __builtin_amdgcn_s_barrier();
      __builtin_amdgcn_sched_barrier(0);
    }
    s0 = (s0 == 2) ? 0 : (s0 + 1);
  }

#undef STAGE
#undef VMW
#undef READF
#undef MM

  // epilogue
#pragma unroll
  for (int mi = 0; mi < 4; ++mi)
#pragma unroll
    for (int ni = 0; ni < 2; ++ni) {
      const int col = col0 + wn * 32 + ni * 16 + l15;
      const float bv = bias0 ? bias0[col] : 0.0f;
#pragma unroll
      for (int r = 0; r < 4; ++r) {
        const int row = row0 + wm * 64 + mi * 16 + quad * 4 + r;
        C[(long)row * ldc + col] = (OutT)(acc[mi][ni][r] * alpha + bv);
      }
    }
}

// grid (S, B): P[b,q,:] = E[b,q,:] * sum_m bit_m(q,:) / rowsum_m / M, bf16.
__global__ __launch_bounds__(256) void softmax_combine(
    const f16* __restrict__ E, const u8* __restrict__ pk, bf16* __restrict__ P) {
  const int q = blockIdx.x;
  const int b = blockIdx.y;
  const int tid = threadIdx.x;
  const int lane = tid & 63;
  const int wv = tid >> 6;
  __shared__ float4 red[4];

  float e[8];
  {
    const f16x8 h = *(const f16x8*)(E + ((long)b * S_ + q) * S_ + tid * 8);
#pragma unroll
    for (int j = 0; j < 8; ++j) e[j] = (float)h[j];
  }
  const unsigned long long mb =
      *(const unsigned long long*)(pk + (long)q * S_ + tid * 8);

  float4 s = {0.f, 0.f, 0.f, 0.f};
#pragma unroll
  for (int j = 0; j < 8; ++j) {
    const unsigned bits = (unsigned)(mb >> (8 * j)) & 0xF;
    const float ev = e[j];
    if (bits & 1) s.x += ev;
    if (bits & 2) s.y += ev;
    if (bits & 4) s.z += ev;
    if (bits & 8) s.w += ev;
  }
#pragma unroll
  for (int o = 32; o > 0; o >>= 1) {
    s.x += __shfl_xor(s.x, o, 64);
    s.y += __shfl_xor(s.y, o, 64);
    s.z += __shfl_xor(s.z, o, 64);
    s.w += __shfl_xor(s.w, o, 64);
  }
  if (lane == 0) red[wv] = s;
  __syncthreads();
  const float4 t0 = red[0], t1 = red[1], t2 = red[2], t3 = red[3];
  const float r0 = 0.25f / (t0.x + t1.x + t2.x + t3.x);
  const float r1 = 0.25f / (t0.y + t1.y + t2.y + t3.y);
  const float r2 = 0.25f / (t0.z + t1.z + t2.z + t3.z);
  const float r3 = 0.25f / (t0.w + t1.w + t2.w + t3.w);

  bf16x8 o;
#pragma unroll
  for (int j = 0; j < 8; ++j) {
    const unsigned bits = (unsigned)(mb >> (8 * j)) & 0xF;
    const float wgt = ((bits & 1) ? r0 : 0.f) + ((bits & 2) ? r1 : 0.f) +
                      ((bits & 4) ? r2 : 0.f) + ((bits & 8) ? r3 : 0.f);
    o[j] = (bf16)(e[j] * wgt);
  }
  *(bf16x8*)(P + ((long)b * S_ + q) * S_ + tid * 8) = o;
}

extern "C" void kernel_launch(void* const* d_in, const int* in_sizes, int n_in,
                              void* d_out, int out_size, void* d_ws, size_t ws_size,
                              hipStream_t stream) {
  const float* x = (const float*)d_in[0];
  const int* masks = (const int*)d_in[1];
  const float* bq = (const float*)d_in[3];
  const float* bk = (const float*)d_in[5];
  const float* bv = (const float*)d_in[7];
  const float* bo = (const float*)d_in[9];
  float* out = (float*)d_out;

  const long DD = (long)D_ * D_;
  const long SD = (long)S_ * D_;
  const long NX = (long)B_ * SD;
  const long SS = (long)S_ * S_;

  // ws: xc 16M | WT 8M | pk 4M | Q/K/V 48M | VT 16M | P 32M | E 32M = 156 MiB
  bf16* xc = (bf16*)d_ws;
  bf16* WqT = xc + NX;  // WkT, WvT, WoT contiguous after
  bf16* WoT = WqT + 3 * DD;
  u8* pk = (u8*)(WoT + DD);    // [S][S] mask bitfield
  bf16* Q = (bf16*)(pk + SS);  // K = Q+NX, V = K+NX (QKV epilogue relies on it)
  bf16* K = Q + NX;
  bf16* V = K + NX;
  bf16* VT = V + NX;
  bf16* P = VT + NX;                   // [B][S][S] bf16
  f16* E = (f16*)(P + (long)B_ * SS);  // [B][S][S] f16
  bf16* attn = Q;                      // attn overwrites dead Q

  dim3 blk(256);
  dim3 blk512(512);

  // fused prep: x->bf16, 4 weight transposes, mask pack (one launch)
  prep<<<dim3(7168), blk, 0, stream>>>(
      x, (const float*)d_in[2], (const float*)d_in[4], (const float*)d_in[6],
      (const float*)d_in[8], masks, xc, WqT, pk);

  // fused Q|K|V projection: [8192,1024] x [1024,3072] (r8-verified gemmA)
  gemmA<bf16, MODE_QKV><<<dim3(24, 32), blk512, 0, stream>>>(
      xc, D_, WqT, 0, D_, Q, D_, bq, bk, bv, 1.0f, D_);

  // VT[b][d][s] = V[b][s][d]
  transposeB<<<dim3(16, 32, B_), blk, 0, stream>>>(V, VT, S_, D_, SD, SD);

  // E = exp(Q K^T / 32) : flat [8192,1024] x K[z][2048,1024] (r8-verified gemmA)
  gemmA<f16, MODE_EXP><<<dim3(16, 32), blk512, 0, stream>>>(
      Q, D_, K, SD, D_, E, S_, nullptr, nullptr, nullptr, 1.0f / 32.0f, D_);

  // P = E * sum_m mask_m / rowsum_m / M
  softmax_combine<<<dim3(S_, B_), blk, 0, stream>>>(E, pk, P);

  // attn = P @ V : flat [8192,2048] x VT[z][1024,2048], K=2048
  // gemmC 256x64 tiles: 16x32 = 512 blocks = 1 round at 2 blocks/CU
  gemmC<bf16, MODE_PV><<<dim3(16, 32), blk512, 0, stream>>>(
      P, S_, VT, SD, S_, attn, D_, nullptr, 1.0f, S_);

  // out = attn @ Wo + bo : fp32 epilogue straight to d_out
  // gemmC 256x64 tiles: 512 blocks = 1 round at 2 blocks/CU
  gemmC<float, MODE_PLAIN><<<dim3(16, 32), blk512, 0, stream>>>(
      attn, D_, WoT, 0, D_, out, D_, bo, 1.0f, D_);
}